// Round 2
// baseline (564.447 us; speedup 1.0000x reference)
//
#include <hip/hip_runtime.h>
#include <hip/hip_bf16.h>

typedef __hip_bfloat16 bf16;

#define B_   4
#define C_   32
#define DW_  64
#define H_   256
#define W_   256
#define P_   65536          // H_*W_
#define SRC_ 32             // source filter grid 32x32

// ---- ws layout (float indices for the small stuff) ----
#define OW1    0            // 64*32
#define OB1    2048         // 64
#define OW3    2112         // 32*32
#define OB3    3136         // 32
#define OWS    3168         // 32*32 (sca)
#define OBS    4192         // 32
#define OW4    4224         // 64*32
#define OB4    6272         // 64
#define OW5    6336         // 32*32
#define OB5    7360         // 32
#define ON1W   7392
#define ON1B   7424
#define ON2W   7456
#define ON2B   7488
#define OBETA  7520
#define OGAMMA 7552
#define OSUMS  7584         // B_*C_ = 128
#define OSVEC  7712         // B_*C_ = 128
#define OFLAG  7900         // int flag: 0 = fp32 inputs, 1 = bf16 inputs
// byte offsets for big bf16 intermediates
#define T1_BOFF  32768ull                       // t1: B*64*P bf16 = 33554432 B
#define G_BOFF   (T1_BOFF + 33554432ull)        // g : B*32*P bf16 = 16777216 B
// total ws need ~= 50.4 MB

__device__ __forceinline__ float bsc2f(bf16 v){ return __bfloat162float(v); }
__device__ __forceinline__ bf16  f2b(float v){ return __float2bfloat16(v); }

template<typename T> __device__ __forceinline__ float ldf(const T* p);
template<> __device__ __forceinline__ float ldf<float>(const float* p){ return *p; }
template<> __device__ __forceinline__ float ldf<bf16>(const bf16* p){ return __bfloat162float(*p); }

template<typename T> __device__ __forceinline__ void stf(T* p, float v);
template<> __device__ __forceinline__ void stf<float>(float* p, float v){ *p = v; }
template<> __device__ __forceinline__ void stf<bf16>(bf16* p, float v){ *p = __float2bfloat16(v); }

template<typename T> struct dtag;
template<> struct dtag<float>{ static constexpr int v = 0; };
template<> struct dtag<bf16>{ static constexpr int v = 1; };

// ---------------- K-1: detect input dtype on device ----------------
// Decode even 16-bit words of inp as bf16. fp32 data -> low mantissa halves,
// ~42%/word have |v|>1e6 or NaN. bf16 data -> |v| < 6 always.
__global__ void k_detect(const unsigned short* __restrict__ raw, int* __restrict__ flag)
{
    int t = threadIdx.x;  // 64 threads
    int bad = 0;
    for (int k = 0; k < 8; ++k) {
        unsigned short u = raw[2 * (t + 64 * k)];
        float v = __uint_as_float(((unsigned int)u) << 16);
        if (!(fabsf(v) < 1e6f)) bad = 1;    // catches huge AND NaN
    }
    int anybad = __any(bad);
    if (t == 0) *flag = anybad ? 0 : 1;
}

// ---------------- K0: weights -> fp32 in ws, zero SCA sums ----------------
template<typename T>
__global__ void k_prep(const T* __restrict__ w1, const T* __restrict__ b1,
                       const T* __restrict__ w3, const T* __restrict__ b3,
                       const T* __restrict__ wsc, const T* __restrict__ bsc_,
                       const T* __restrict__ w4, const T* __restrict__ b4,
                       const T* __restrict__ w5, const T* __restrict__ b5,
                       const T* __restrict__ n1w, const T* __restrict__ n1b,
                       const T* __restrict__ n2w, const T* __restrict__ n2b,
                       const T* __restrict__ bet, const T* __restrict__ gam,
                       float* __restrict__ wsf, const int* __restrict__ flag)
{
    if (*flag != dtag<T>::v) return;
    int t = threadIdx.x;
    for (int i = t; i < 2048; i += 256) wsf[OW1 + i] = ldf<T>(w1 + i);
    for (int i = t; i < 64;   i += 256) wsf[OB1 + i] = ldf<T>(b1 + i);
    for (int i = t; i < 1024; i += 256) wsf[OW3 + i] = ldf<T>(w3 + i);
    for (int i = t; i < 32;   i += 256) wsf[OB3 + i] = ldf<T>(b3 + i);
    for (int i = t; i < 1024; i += 256) wsf[OWS + i] = ldf<T>(wsc + i);
    for (int i = t; i < 32;   i += 256) wsf[OBS + i] = ldf<T>(bsc_ + i);
    for (int i = t; i < 2048; i += 256) wsf[OW4 + i] = ldf<T>(w4 + i);
    for (int i = t; i < 64;   i += 256) wsf[OB4 + i] = ldf<T>(b4 + i);
    for (int i = t; i < 1024; i += 256) wsf[OW5 + i] = ldf<T>(w5 + i);
    for (int i = t; i < 32;   i += 256) wsf[OB5 + i] = ldf<T>(b5 + i);
    for (int i = t; i < 32;   i += 256) wsf[ON1W + i] = ldf<T>(n1w + i);
    for (int i = t; i < 32;   i += 256) wsf[ON1B + i] = ldf<T>(n1b + i);
    for (int i = t; i < 32;   i += 256) wsf[ON2W + i] = ldf<T>(n2w + i);
    for (int i = t; i < 32;   i += 256) wsf[ON2B + i] = ldf<T>(n2b + i);
    for (int i = t; i < 32;   i += 256) wsf[OBETA + i] = ldf<T>(bet + i);
    for (int i = t; i < 32;   i += 256) wsf[OGAMMA + i] = ldf<T>(gam + i);
    for (int i = t; i < 128;  i += 256) wsf[OSUMS + i] = 0.f;
}

// ---------------- K1: LayerNorm2d (over C) + conv1 (32->64) ----------------
template<typename T>
__global__ __launch_bounds__(256) void k_ln1_conv1(const T* __restrict__ inp,
        const float* __restrict__ wsf, bf16* __restrict__ t1,
        const int* __restrict__ flag)
{
    if (*flag != dtag<T>::v) return;
    int tid = blockIdx.x * 256 + threadIdx.x;   // 0 .. B*P-1
    int b = tid >> 16;
    int p = tid & 65535;
    const T* ip = inp + (size_t)b * C_ * P_ + p;
    float v[C_];
    float m = 0.f;
    #pragma unroll
    for (int ch = 0; ch < C_; ++ch) { v[ch] = ldf<T>(ip + ch * P_); m += v[ch]; }
    m *= (1.f / C_);
    float var = 0.f;
    #pragma unroll
    for (int ch = 0; ch < C_; ++ch) { float d = v[ch] - m; var += d * d; }
    var *= (1.f / C_);
    float inv = rsqrtf(var + 1e-6f);
    #pragma unroll
    for (int ch = 0; ch < C_; ++ch)
        v[ch] = (v[ch] - m) * inv * wsf[ON1W + ch] + wsf[ON1B + ch];

    bf16* op = t1 + (size_t)b * DW_ * P_ + p;
    #pragma unroll 4
    for (int o = 0; o < DW_; ++o) {
        float acc = wsf[OB1 + o];
        #pragma unroll
        for (int ch = 0; ch < C_; ++ch) acc += v[ch] * wsf[OW1 + o * C_ + ch];
        op[o * P_] = f2b(acc);
    }
}

// ------ K2: bilinear-upsampled per-pixel 3x3 DDF + SimpleGate + SCA sums ------
template<typename T>
__global__ __launch_bounds__(256) void k_ddf(const bf16* __restrict__ t1,
        const T* __restrict__ cw, bf16* __restrict__ g, float* __restrict__ sums,
        const int* __restrict__ flag)
{
    if (*flag != dtag<T>::v) return;
    __shared__ float red[4 * C_];
    int tid = blockIdx.x * 256 + threadIdx.x;
    int b = tid >> 16;
    int p = tid & 65535;
    int h = p >> 8, w = p & 255;

    // bilinear setup: half-pixel centers, clamped indices (== jax linear / torch AC=False)
    float shf = (h + 0.5f) * 0.125f - 0.5f;
    float swf = (w + 0.5f) * 0.125f - 0.5f;
    int h0 = (int)floorf(shf); float fh = shf - (float)h0;
    int w0 = (int)floorf(swf); float fw = swf - (float)w0;
    int h0c = max(h0, 0), h1c = min(h0 + 1, SRC_ - 1);
    int w0c = max(w0, 0), w1c = min(w0 + 1, SRC_ - 1);
    int o00 = h0c * SRC_ + w0c, o01 = h0c * SRC_ + w1c;
    int o10 = h1c * SRC_ + w0c, o11 = h1c * SRC_ + w1c;
    float c00 = (1.f - fh) * (1.f - fw), c01 = (1.f - fh) * fw;
    float c10 = fh * (1.f - fw),         c11 = fh * fw;

    const bf16* t1b = t1 + (size_t)b * DW_ * P_;
    const T* cwb = cw + (size_t)b * DW_ * 9 * (SRC_ * SRC_);
    bf16* gp = g + (size_t)b * C_ * P_ + p;
    int lane = threadIdx.x & 63, wid = threadIdx.x >> 6;

    for (int cp = 0; cp < C_; ++cp) {
        float acc1 = 0.f, acc2 = 0.f;
        #pragma unroll
        for (int i = 0; i < 3; ++i) {
            int hh = h + i - 1;
            bool vh = ((unsigned)hh < (unsigned)H_);
            #pragma unroll
            for (int j = 0; j < 3; ++j) {
                int ww = w + j - 1;
                bool vv = vh && ((unsigned)ww < (unsigned)W_);
                int t = i * 3 + j;
                int poff = hh * W_ + ww;
                float p1 = vv ? bsc2f(t1b[cp * P_ + poff]) : 0.f;
                float p2 = vv ? bsc2f(t1b[(cp + 32) * P_ + poff]) : 0.f;
                const T* c1 = cwb + (cp * 9 + t) * (SRC_ * SRC_);
                const T* c2 = cwb + ((cp + 32) * 9 + t) * (SRC_ * SRC_);
                float f1 = c00 * ldf<T>(c1 + o00) + c01 * ldf<T>(c1 + o01)
                         + c10 * ldf<T>(c1 + o10) + c11 * ldf<T>(c1 + o11);
                float f2 = c00 * ldf<T>(c2 + o00) + c01 * ldf<T>(c2 + o01)
                         + c10 * ldf<T>(c2 + o10) + c11 * ldf<T>(c2 + o11);
                acc1 += p1 * f1;
                acc2 += p2 * f2;
            }
        }
        float gv = acc1 * acc2;
        gp[cp * P_] = f2b(gv);
        // wave-64 reduce for the SCA mean
        float s = gv;
        #pragma unroll
        for (int off = 32; off >= 1; off >>= 1) s += __shfl_xor(s, off, 64);
        if (lane == 0) red[wid * C_ + cp] = s;
    }
    __syncthreads();
    if (threadIdx.x < C_) {
        float tot = red[threadIdx.x] + red[C_ + threadIdx.x]
                  + red[2 * C_ + threadIdx.x] + red[3 * C_ + threadIdx.x];
        atomicAdd(&sums[b * C_ + threadIdx.x], tot);
    }
}

// ---------------- K3: SCA vector: s = sca_w @ mean + sca_b (dtype-free) ----------------
__global__ void k_sca(float* __restrict__ wsf)
{
    int t = threadIdx.x;            // 128 threads
    int b = t >> 5, o = t & 31;
    float acc = wsf[OBS + o];
    #pragma unroll
    for (int ch = 0; ch < C_; ++ch)
        acc += wsf[OWS + o * C_ + ch] * (wsf[OSUMS + b * C_ + ch] * (1.f / (float)P_));
    wsf[OSVEC + b * C_ + o] = acc;
}

// ------- K4: scale, conv3, +beta residual, LN2, conv4, gate, conv5, out -------
template<typename T>
__global__ __launch_bounds__(256) void k_tail(const T* __restrict__ inp,
        const bf16* __restrict__ g, const float* __restrict__ wsf,
        T* __restrict__ out, const int* __restrict__ flag)
{
    if (*flag != dtag<T>::v) return;
    int tid = blockIdx.x * 256 + threadIdx.x;
    int b = tid >> 16;
    int p = tid & 65535;
    const bf16* gp = g + (size_t)b * C_ * P_ + p;
    const T* ip = inp + (size_t)b * C_ * P_ + p;

    float x[C_];
    #pragma unroll
    for (int ch = 0; ch < C_; ++ch)
        x[ch] = bsc2f(gp[ch * P_]) * wsf[OSVEC + b * C_ + ch];

    // conv3 + beta residual -> y
    float y[C_];
    #pragma unroll 4
    for (int o = 0; o < C_; ++o) {
        float acc = wsf[OB3 + o];
        #pragma unroll
        for (int ch = 0; ch < C_; ++ch) acc += x[ch] * wsf[OW3 + o * C_ + ch];
        y[o] = ldf<T>(ip + o * P_) + acc * wsf[OBETA + o];
    }

    // LN2
    float m = 0.f;
    #pragma unroll
    for (int ch = 0; ch < C_; ++ch) m += y[ch];
    m *= (1.f / C_);
    float var = 0.f;
    #pragma unroll
    for (int ch = 0; ch < C_; ++ch) { float d = y[ch] - m; var += d * d; }
    var *= (1.f / C_);
    float inv = rsqrtf(var + 1e-6f);
    float yn[C_];
    #pragma unroll
    for (int ch = 0; ch < C_; ++ch)
        yn[ch] = (y[ch] - m) * inv * wsf[ON2W + ch] + wsf[ON2B + ch];

    // conv4 (32->64) + SimpleGate
    float u[C_];
    #pragma unroll 2
    for (int o = 0; o < C_; ++o) {
        float a = wsf[OB4 + o], bb = wsf[OB4 + 32 + o];
        #pragma unroll
        for (int ch = 0; ch < C_; ++ch) {
            a  += yn[ch] * wsf[OW4 + o * C_ + ch];
            bb += yn[ch] * wsf[OW4 + (o + 32) * C_ + ch];
        }
        u[o] = a * bb;
    }

    // conv5 + gamma residual -> out
    T* op = out + (size_t)b * C_ * P_ + p;
    #pragma unroll 4
    for (int o = 0; o < C_; ++o) {
        float acc = wsf[OB5 + o];
        #pragma unroll
        for (int ch = 0; ch < C_; ++ch) acc += u[ch] * wsf[OW5 + o * C_ + ch];
        stf<T>(op + o * P_, y[o] + acc * wsf[OGAMMA + o]);
    }
}

extern "C" void kernel_launch(void* const* d_in, const int* in_sizes, int n_in,
                              void* d_out, int out_size, void* d_ws, size_t ws_size,
                              hipStream_t stream)
{
    float* wsf = (float*)d_ws;
    char* wsb = (char*)d_ws;
    bf16* t1 = (bf16*)(wsb + T1_BOFF);
    bf16* g  = (bf16*)(wsb + G_BOFF);
    int* flag = (int*)(wsf + OFLAG);

    k_detect<<<1, 64, 0, stream>>>((const unsigned short*)d_in[0], flag);

    int nblk = (B_ * P_) / 256;   // 1024

    // ---- fp32 variant ----
    {
        const float* inp = (const float*)d_in[0];
        const float* cw2 = (const float*)d_in[1];
        k_prep<float><<<1, 256, 0, stream>>>(
            (const float*)d_in[2], (const float*)d_in[3], (const float*)d_in[4],
            (const float*)d_in[5], (const float*)d_in[6], (const float*)d_in[7],
            (const float*)d_in[8], (const float*)d_in[9], (const float*)d_in[10],
            (const float*)d_in[11], (const float*)d_in[12], (const float*)d_in[13],
            (const float*)d_in[14], (const float*)d_in[15], (const float*)d_in[16],
            (const float*)d_in[17], wsf, flag);
        k_ln1_conv1<float><<<nblk, 256, 0, stream>>>(inp, wsf, t1, flag);
        k_ddf<float><<<nblk, 256, 0, stream>>>(t1, cw2, g, wsf + OSUMS, flag);
    }
    // ---- bf16 variant ----
    {
        const bf16* inp = (const bf16*)d_in[0];
        const bf16* cw2 = (const bf16*)d_in[1];
        k_prep<bf16><<<1, 256, 0, stream>>>(
            (const bf16*)d_in[2], (const bf16*)d_in[3], (const bf16*)d_in[4],
            (const bf16*)d_in[5], (const bf16*)d_in[6], (const bf16*)d_in[7],
            (const bf16*)d_in[8], (const bf16*)d_in[9], (const bf16*)d_in[10],
            (const bf16*)d_in[11], (const bf16*)d_in[12], (const bf16*)d_in[13],
            (const bf16*)d_in[14], (const bf16*)d_in[15], (const bf16*)d_in[16],
            (const bf16*)d_in[17], wsf, flag);
        k_ln1_conv1<bf16><<<nblk, 256, 0, stream>>>(inp, wsf, t1, flag);
        k_ddf<bf16><<<nblk, 256, 0, stream>>>(t1, cw2, g, wsf + OSUMS, flag);
    }

    k_sca<<<1, 128, 0, stream>>>(wsf);

    k_tail<float><<<nblk, 256, 0, stream>>>((const float*)d_in[0], g, wsf,
                                            (float*)d_out, flag);
    k_tail<bf16><<<nblk, 256, 0, stream>>>((const bf16*)d_in[0], g, wsf,
                                           (bf16*)d_out, flag);
}

// Round 3
// 357.200 us; speedup vs baseline: 1.5802x; 1.5802x over previous
//
#include <hip/hip_runtime.h>
#include <hip/hip_bf16.h>

typedef __hip_bfloat16 bf16;

#define B_   4
#define C_   32
#define DW_  64
#define H_   256
#define W_   256
#define P_   65536          // H_*W_
#define SRC_ 32             // source filter grid 32x32
#define PP_  66564          // padded plane 258*258

// ---- ws layout (float indices for the small stuff) ----
#define OW1    0            // 64*32
#define OB1    2048         // 64
#define OW3    2112         // 32*32
#define OB3    3136         // 32
#define OWS    3168         // 32*32 (sca)
#define OBS    4192         // 32
#define OW4    4224         // 64*32
#define OB4    6272         // 64
#define OW5    6336         // 32*32
#define OB5    7360         // 32
#define ON1W   7392
#define ON1B   7424
#define ON2W   7456
#define ON2B   7488
#define OBETA  7520
#define OGAMMA 7552
#define OSUMS  7584         // B_*C_ = 128
#define OSVEC  7712         // B_*C_ = 128
#define OFLAG  7900         // int flag: 0 = fp32 inputs, 1 = bf16 inputs
// byte offsets for big intermediates
#define CWF_BOFF 32768ull                        // cwf fp32: 4*64*9*1024*4 = 9437184 B
#define T1_BOFF  (CWF_BOFF + 9437184ull)         // t1 padded bf16: 256*66564*2 = 34080768 B
#define G_BOFF   (T1_BOFF + 34080768ull)         // g bf16: 16777216 B
// total ws ~= 60.3 MB

__device__ __forceinline__ bf16  f2b(float v){ return __float2bfloat16(v); }
__device__ __forceinline__ float bfu(unsigned short u){ return __uint_as_float(((unsigned int)u) << 16); }

template<typename T> __device__ __forceinline__ float ldf(const T* p);
template<> __device__ __forceinline__ float ldf<float>(const float* p){ return *p; }
template<> __device__ __forceinline__ float ldf<bf16>(const bf16* p){ return __bfloat162float(*p); }

template<typename T> __device__ __forceinline__ void stf(T* p, float v);
template<> __device__ __forceinline__ void stf<float>(float* p, float v){ *p = v; }
template<> __device__ __forceinline__ void stf<bf16>(bf16* p, float v){ *p = __float2bfloat16(v); }

template<typename T> struct dtag;
template<> struct dtag<float>{ static constexpr int v = 0; };
template<> struct dtag<bf16>{ static constexpr int v = 1; };

__device__ __forceinline__ float d4(float4 a, float4 b){
    return a.x*b.x + a.y*b.y + a.z*b.z + a.w*b.w;
}

// ---------------- dtype detector (fp32 low-mantissa halves decode huge/NaN) ----------------
__global__ void k_detect(const unsigned short* __restrict__ raw, int* __restrict__ flag)
{
    int t = threadIdx.x;  // 64 threads
    int bad = 0;
    for (int k = 0; k < 8; ++k) {
        unsigned short u = raw[2 * (t + 64 * k)];
        float v = __uint_as_float(((unsigned int)u) << 16);
        if (!(fabsf(v) < 1e6f)) bad = 1;
    }
    int anybad = __any(bad);
    if (t == 0) *flag = anybad ? 0 : 1;
}

// ---------------- weights -> fp32 in ws, zero SCA sums ----------------
template<typename T>
__global__ void k_prep(const T* __restrict__ w1, const T* __restrict__ b1,
                       const T* __restrict__ w3, const T* __restrict__ b3,
                       const T* __restrict__ wsc, const T* __restrict__ bsc_,
                       const T* __restrict__ w4, const T* __restrict__ b4,
                       const T* __restrict__ w5, const T* __restrict__ b5,
                       const T* __restrict__ n1w, const T* __restrict__ n1b,
                       const T* __restrict__ n2w, const T* __restrict__ n2b,
                       const T* __restrict__ bet, const T* __restrict__ gam,
                       float* __restrict__ wsf, const int* __restrict__ flag)
{
    if (*flag != dtag<T>::v) return;
    int t = threadIdx.x;
    for (int i = t; i < 2048; i += 256) wsf[OW1 + i] = ldf<T>(w1 + i);
    for (int i = t; i < 64;   i += 256) wsf[OB1 + i] = ldf<T>(b1 + i);
    for (int i = t; i < 1024; i += 256) wsf[OW3 + i] = ldf<T>(w3 + i);
    for (int i = t; i < 32;   i += 256) wsf[OB3 + i] = ldf<T>(b3 + i);
    for (int i = t; i < 1024; i += 256) wsf[OWS + i] = ldf<T>(wsc + i);
    for (int i = t; i < 32;   i += 256) wsf[OBS + i] = ldf<T>(bsc_ + i);
    for (int i = t; i < 2048; i += 256) wsf[OW4 + i] = ldf<T>(w4 + i);
    for (int i = t; i < 64;   i += 256) wsf[OB4 + i] = ldf<T>(b4 + i);
    for (int i = t; i < 1024; i += 256) wsf[OW5 + i] = ldf<T>(w5 + i);
    for (int i = t; i < 32;   i += 256) wsf[OB5 + i] = ldf<T>(b5 + i);
    for (int i = t; i < 32;   i += 256) wsf[ON1W + i] = ldf<T>(n1w + i);
    for (int i = t; i < 32;   i += 256) wsf[ON1B + i] = ldf<T>(n1b + i);
    for (int i = t; i < 32;   i += 256) wsf[ON2W + i] = ldf<T>(n2w + i);
    for (int i = t; i < 32;   i += 256) wsf[ON2B + i] = ldf<T>(n2b + i);
    for (int i = t; i < 32;   i += 256) wsf[OBETA + i] = ldf<T>(bet + i);
    for (int i = t; i < 32;   i += 256) wsf[OGAMMA + i] = ldf<T>(gam + i);
    for (int i = t; i < 128;  i += 256) wsf[OSUMS + i] = 0.f;
}

// ---------------- cw2 -> fp32 copy (makes k_ddf dtype-free) ----------------
template<typename T>
__global__ void k_cwf(const T* __restrict__ cw, float* __restrict__ cwf,
                      const int* __restrict__ flag)
{
    if (*flag != dtag<T>::v) return;
    int i0 = blockIdx.x * 256 + threadIdx.x;
    const int n = B_ * DW_ * 9 * 1024;
    for (int i = i0; i < n; i += 262144) cwf[i] = ldf<T>(cw + i);
}

// ---------------- zero the padded borders of t1 ----------------
__global__ void k_zpad(unsigned short* __restrict__ t1u)
{
    unsigned short* pl = t1u + (size_t)blockIdx.x * PP_;   // 256 planes
    int t = threadIdx.x;
    for (int i = t; i < 258; i += 256) {
        pl[i] = 0;
        pl[257 * 258 + i] = 0;
    }
    // rows 1..256, cols 0 and 257
    pl[(t + 1) * 258] = 0;
    pl[(t + 1) * 258 + 257] = 0;
}

// ---------------- LayerNorm2d + conv1 (32->64), writes padded t1 ----------------
template<typename T>
__global__ __launch_bounds__(256) void k_ln1_conv1(const T* __restrict__ inp,
        const float* __restrict__ wsf, bf16* __restrict__ t1p,
        const int* __restrict__ flag)
{
    if (*flag != dtag<T>::v) return;
    int tid = blockIdx.x * 256 + threadIdx.x;   // 0 .. B*P-1
    int b = tid >> 16;
    int p = tid & 65535;
    int h = p >> 8, w = p & 255;
    const T* ip = inp + (size_t)b * C_ * P_ + p;
    float v[C_];
    float m = 0.f;
    #pragma unroll
    for (int ch = 0; ch < C_; ++ch) { v[ch] = ldf<T>(ip + ch * P_); m += v[ch]; }
    m *= (1.f / C_);
    float var = 0.f;
    #pragma unroll
    for (int ch = 0; ch < C_; ++ch) { float d = v[ch] - m; var += d * d; }
    var *= (1.f / C_);
    float inv = rsqrtf(var + 1e-6f);
    #pragma unroll
    for (int ch = 0; ch < C_; ++ch)
        v[ch] = (v[ch] - m) * inv * wsf[ON1W + ch] + wsf[ON1B + ch];

    bf16* op = t1p + (size_t)(b * DW_) * PP_ + (h + 1) * 258 + (w + 1);
    #pragma unroll 4
    for (int o = 0; o < DW_; ++o) {
        float acc = wsf[OB1 + o];
        #pragma unroll
        for (int ch = 0; ch < C_; ++ch) acc += v[ch] * wsf[OW1 + o * C_ + ch];
        op[(size_t)o * PP_] = f2b(acc);
    }
}

// ------ DDF v2: wave = 8x8 cell, filter corners staged in LDS, + SimpleGate ------
// block = 2x2 cells (256 threads), dtype-free.
__global__ __launch_bounds__(256, 4) void k_ddf(const unsigned short* __restrict__ t1u,
        const float* __restrict__ cwf, bf16* __restrict__ g)
{
    __shared__ float V4[9216];   // [ch*9+tap][4 rows][4 cols] fp32, 36864 B

    int bid = blockIdx.x;
    int b = bid >> 8;
    int tb = bid & 255;
    int bch = (tb >> 4) * 2;     // base cell row (2x2 cells per block)
    int bcw = (tb & 15) * 2;

    // --- cooperative staging of the 4x4 filter-corner region for all 576 (ch,tap) ---
    {
        const float* cb = cwf + (size_t)b * (DW_ * 9 * 1024);
        int rof[4], cof[4];
        #pragma unroll
        for (int k = 0; k < 4; ++k) {
            int rr = bch - 1 + k; rr = rr < 0 ? 0 : (rr > 31 ? 31 : rr);
            int cc = bcw - 1 + k; cc = cc < 0 ? 0 : (cc > 31 ? 31 : cc);
            rof[k] = rr * SRC_; cof[k] = cc;
        }
        for (int it = 0; it < 36; ++it) {
            int idx = it * 256 + threadIdx.x;        // 0..9215
            int cc = idx & 3, rr = (idx >> 2) & 3, pt = idx >> 4;
            V4[idx] = cb[pt * 1024 + rof[rr] + cof[cc]];
        }
    }
    __syncthreads();

    int wid = threadIdx.x >> 6, lane = threadIdx.x & 63;
    int rbase = wid >> 1, cbase = wid & 1;
    int cellh = bch + rbase, cellw = bcw + cbase;
    int r = lane >> 3, c = lane & 7;
    int h = cellh * 8 + r, w = cellw * 8 + c;

    // bilinear weights over the 3x3 corner window (rows rbase..rbase+2 of the 4x4)
    float wr0, wr1, wr2, wc0, wc1, wc2;
    {
        int q = r + 4; int ai = q >> 3; float fh = (float)((q & 7)) * 0.125f + 0.0625f;
        wr0 = ai ? 0.f : 1.f - fh;  wr1 = ai ? 1.f - fh : fh;  wr2 = ai ? fh : 0.f;
        q = c + 4; int bi = q >> 3; float fw = (float)((q & 7)) * 0.125f + 0.0625f;
        wc0 = bi ? 0.f : 1.f - fw;  wc1 = bi ? 1.f - fw : fw;  wc2 = bi ? fw : 0.f;
    }
    // expand to 4-wide rows aligned with cbase so inner loop is pure dot4 (no selects)
    float4 wk0, wk1, wk2;
    {
        float z = 0.f;
        float a0 = wr0 * wc0, a1 = wr0 * wc1, a2 = wr0 * wc2;
        wk0 = cbase ? make_float4(z, a0, a1, a2) : make_float4(a0, a1, a2, z);
        a0 = wr1 * wc0; a1 = wr1 * wc1; a2 = wr1 * wc2;
        wk1 = cbase ? make_float4(z, a0, a1, a2) : make_float4(a0, a1, a2, z);
        a0 = wr2 * wc0; a1 = wr2 * wc1; a2 = wr2 * wc2;
        wk2 = cbase ? make_float4(z, a0, a1, a2) : make_float4(a0, a1, a2, z);
    }

    const float4* Vf4 = (const float4*)V4;
    int hw0 = (h + 0) * 258 + w;    // padded base: tap (i,j) at hw0 + i*258 + j
    bf16* gp = g + (size_t)(b * C_) * P_ + h * 256 + w;

    for (int cp = 0; cp < C_; ++cp) {
        const unsigned short* pl1 = t1u + (size_t)(b * DW_ + cp) * PP_;
        const unsigned short* pl2 = pl1 + (size_t)C_ * PP_;
        const float4* q1 = Vf4 + (cp * 9) * 4 + rbase;
        const float4* q2 = Vf4 + ((cp + 32) * 9) * 4 + rbase;
        float acc1 = 0.f, acc2 = 0.f;
        #pragma unroll
        for (int i = 0; i < 3; ++i) {
            #pragma unroll
            for (int j = 0; j < 3; ++j) {
                int tap = i * 3 + j;
                float4 A0 = q1[tap * 4 + 0], A1 = q1[tap * 4 + 1], A2 = q1[tap * 4 + 2];
                float4 B0 = q2[tap * 4 + 0], B1 = q2[tap * 4 + 1], B2 = q2[tap * 4 + 2];
                float f1 = d4(wk0, A0) + d4(wk1, A1) + d4(wk2, A2);
                float f2 = d4(wk0, B0) + d4(wk1, B1) + d4(wk2, B2);
                float p1 = bfu(pl1[hw0 + i * 258 + j]);
                float p2 = bfu(pl2[hw0 + i * 258 + j]);
                acc1 += p1 * f1;
                acc2 += p2 * f2;
            }
        }
        gp[cp * P_] = f2b(acc1 * acc2);
    }
}

// ---------------- per-(b,ch) sums of g for SCA ----------------
__global__ void k_rsum(const unsigned int* __restrict__ gu, float* __restrict__ sums)
{
    __shared__ float red[4];
    int blk = blockIdx.x;            // 512 blocks
    int b = blk >> 7, ch = (blk >> 2) & 31, q = blk & 3;
    int base32 = (b * 32 + ch) * 32768 + q * 8192;   // u32 index
    int t = threadIdx.x;
    float s = 0.f;
    for (int it = 0; it < 32; ++it) {
        unsigned int u = gu[base32 + it * 256 + t];
        s += __uint_as_float(u << 16);
        s += __uint_as_float(u & 0xFFFF0000u);
    }
    #pragma unroll
    for (int off = 32; off >= 1; off >>= 1) s += __shfl_xor(s, off, 64);
    int lane = t & 63, wid = t >> 6;
    if (lane == 0) red[wid] = s;
    __syncthreads();
    if (t == 0) atomicAdd(&sums[b * 32 + ch], red[0] + red[1] + red[2] + red[3]);
}

// ---------------- SCA vector: s = sca_w @ mean + sca_b ----------------
__global__ void k_sca(float* __restrict__ wsf)
{
    int t = threadIdx.x;            // 128 threads
    int b = t >> 5, o = t & 31;
    float acc = wsf[OBS + o];
    #pragma unroll
    for (int ch = 0; ch < C_; ++ch)
        acc += wsf[OWS + o * C_ + ch] * (wsf[OSUMS + b * C_ + ch] * (1.f / (float)P_));
    wsf[OSVEC + b * C_ + o] = acc;
}

// ------- tail: scale, conv3, +beta residual, LN2, conv4, gate, conv5, out -------
template<typename T>
__global__ __launch_bounds__(256) void k_tail(const T* __restrict__ inp,
        const bf16* __restrict__ g, const float* __restrict__ wsf,
        T* __restrict__ out, const int* __restrict__ flag)
{
    if (*flag != dtag<T>::v) return;
    int tid = blockIdx.x * 256 + threadIdx.x;
    int b = tid >> 16;
    int p = tid & 65535;
    const bf16* gp = g + (size_t)b * C_ * P_ + p;
    const T* ip = inp + (size_t)b * C_ * P_ + p;

    float x[C_];
    #pragma unroll
    for (int ch = 0; ch < C_; ++ch)
        x[ch] = __bfloat162float(gp[ch * P_]) * wsf[OSVEC + b * C_ + ch];

    float y[C_];
    #pragma unroll 4
    for (int o = 0; o < C_; ++o) {
        float acc = wsf[OB3 + o];
        #pragma unroll
        for (int ch = 0; ch < C_; ++ch) acc += x[ch] * wsf[OW3 + o * C_ + ch];
        y[o] = ldf<T>(ip + o * P_) + acc * wsf[OBETA + o];
    }

    float m = 0.f;
    #pragma unroll
    for (int ch = 0; ch < C_; ++ch) m += y[ch];
    m *= (1.f / C_);
    float var = 0.f;
    #pragma unroll
    for (int ch = 0; ch < C_; ++ch) { float d = y[ch] - m; var += d * d; }
    var *= (1.f / C_);
    float inv = rsqrtf(var + 1e-6f);
    float yn[C_];
    #pragma unroll
    for (int ch = 0; ch < C_; ++ch)
        yn[ch] = (y[ch] - m) * inv * wsf[ON2W + ch] + wsf[ON2B + ch];

    float u[C_];
    #pragma unroll 2
    for (int o = 0; o < C_; ++o) {
        float a = wsf[OB4 + o], bb = wsf[OB4 + 32 + o];
        #pragma unroll
        for (int ch = 0; ch < C_; ++ch) {
            a  += yn[ch] * wsf[OW4 + o * C_ + ch];
            bb += yn[ch] * wsf[OW4 + (o + 32) * C_ + ch];
        }
        u[o] = a * bb;
    }

    T* op = out + (size_t)b * C_ * P_ + p;
    #pragma unroll 4
    for (int o = 0; o < C_; ++o) {
        float acc = wsf[OB5 + o];
        #pragma unroll
        for (int ch = 0; ch < C_; ++ch) acc += u[ch] * wsf[OW5 + o * C_ + ch];
        stf<T>(op + o * P_, y[o] + acc * wsf[OGAMMA + o]);
    }
}

extern "C" void kernel_launch(void* const* d_in, const int* in_sizes, int n_in,
                              void* d_out, int out_size, void* d_ws, size_t ws_size,
                              hipStream_t stream)
{
    float* wsf = (float*)d_ws;
    char* wsb = (char*)d_ws;
    float* cwf = (float*)(wsb + CWF_BOFF);
    bf16* t1p = (bf16*)(wsb + T1_BOFF);
    bf16* g   = (bf16*)(wsb + G_BOFF);
    int* flag = (int*)(wsf + OFLAG);

    k_detect<<<1, 64, 0, stream>>>((const unsigned short*)d_in[0], flag);

    int nblk = (B_ * P_) / 256;   // 1024

    // prep + cw conversion, both dtype variants (dead one exits on flag)
    k_prep<float><<<1, 256, 0, stream>>>(
        (const float*)d_in[2], (const float*)d_in[3], (const float*)d_in[4],
        (const float*)d_in[5], (const float*)d_in[6], (const float*)d_in[7],
        (const float*)d_in[8], (const float*)d_in[9], (const float*)d_in[10],
        (const float*)d_in[11], (const float*)d_in[12], (const float*)d_in[13],
        (const float*)d_in[14], (const float*)d_in[15], (const float*)d_in[16],
        (const float*)d_in[17], wsf, flag);
    k_prep<bf16><<<1, 256, 0, stream>>>(
        (const bf16*)d_in[2], (const bf16*)d_in[3], (const bf16*)d_in[4],
        (const bf16*)d_in[5], (const bf16*)d_in[6], (const bf16*)d_in[7],
        (const bf16*)d_in[8], (const bf16*)d_in[9], (const bf16*)d_in[10],
        (const bf16*)d_in[11], (const bf16*)d_in[12], (const bf16*)d_in[13],
        (const bf16*)d_in[14], (const bf16*)d_in[15], (const bf16*)d_in[16],
        (const bf16*)d_in[17], wsf, flag);
    k_cwf<float><<<1024, 256, 0, stream>>>((const float*)d_in[1], cwf, flag);
    k_cwf<bf16><<<1024, 256, 0, stream>>>((const bf16*)d_in[1], cwf, flag);

    k_zpad<<<256, 256, 0, stream>>>((unsigned short*)t1p);

    k_ln1_conv1<float><<<nblk, 256, 0, stream>>>((const float*)d_in[0], wsf, t1p, flag);
    k_ln1_conv1<bf16><<<nblk, 256, 0, stream>>>((const bf16*)d_in[0], wsf, t1p, flag);

    k_ddf<<<1024, 256, 0, stream>>>((const unsigned short*)t1p, cwf, g);

    k_rsum<<<512, 256, 0, stream>>>((const unsigned int*)g, wsf + OSUMS);
    k_sca<<<1, 128, 0, stream>>>(wsf);

    k_tail<float><<<nblk, 256, 0, stream>>>((const float*)d_in[0], g, wsf,
                                            (float*)d_out, flag);
    k_tail<bf16><<<nblk, 256, 0, stream>>>((const bf16*)d_in[0], g, wsf,
                                           (bf16*)d_out, flag);
}